// Round 13
// baseline (35.995 us; speedup 1.0000x reference)
//
#include <hip/hip_runtime.h>
#include <hip/hip_bf16.h>

// QuantumAttention: out[b,s,e] = sum_q q[b,s,q] * W_dec[e,q] + x[b,s,e]
//   angles = x @ W_enc^T, c = cos(angles)
//   q[0] = prod(c[1..7]); q[i] = prod(c[0..i])
//
// R13: MFMA encode. The 9-variant 31us plateau is dependent-chain latency
// (6-deep DPP reduce + barrier lockstep). angles = [64x1024]@[1024x8] GEMM
// -> mfma_f32_16x16x32_bf16, K-loop of 32 INDEPENDENT MFMAs per 16-token
// tile; the cross-lane reduction disappears into the matrix pipe. q ends
// lane-local (C: col=lane&15=q, row=(lane>>4)*4+reg=token; m89-verified),
// cumprod = 3-step DPP scan. One barrier; streaming decode (x re-read,
// L2-hot) + NT stores. W_enc staged once as pre-swizzled bf16 B-fragments
// in LDS (32KB, conflict-free b128).

typedef float v2f __attribute__((ext_vector_type(2)));
typedef float v4f __attribute__((ext_vector_type(4)));
typedef short bf16x8 __attribute__((ext_vector_type(8)));

#define EDIM 1024
#define QDIM 8
#define NTOK 16384
#define BLOCK 256
#define TOKPB 64
#define GRID (NTOK / TOKPB)   // 256 blocks = 1 per CU
#define NKK (EDIM / 32)       // 32 K-steps

__device__ __forceinline__ short f2bf(float f) {
    __hip_bfloat16 h = __float2bfloat16(f);   // RNE; compiler emits v_cvt
    return *reinterpret_cast<short*>(&h);
}

// inclusive product-scan step within 16-lane rows (row_shr, bound_ctrl)
template<int K>
__device__ __forceinline__ float scan_mul_step(float p, int laneq) {
    int m = __builtin_amdgcn_update_dpp(0, __float_as_int(p), 0x110 | K, 0xF, 0xF, true);
    float tmul = (laneq >= K) ? __int_as_float(m) : 1.0f;
    return p * tmul;
}

__global__ __launch_bounds__(BLOCK)
void qattn_kernel(const float* __restrict__ x,
                  const float* __restrict__ W_enc,   // [Q][E]
                  const float* __restrict__ W_dec,   // [E][Q]
                  float* __restrict__ out)
{
    // B-fragments: slot = kk*64 + lane, 8 bf16 each -> 32 KB
    __shared__ short Blds[NKK * 64 * 8];
    __shared__ float qv_s[TOKPB][QDIM];    // 2 KB

    const int t    = threadIdx.x;
    const int lane = t & 63;
    const int wave = t >> 6;
    const int tok0 = blockIdx.x * TOKPB;

    // ---- prologue: stage W_enc as bf16 B-fragments (each thread 8 slots) ----
    // slot s: kk = s>>6, l = s&63; q = l&15, kgroup = l>>4;
    // elems j=0..7: W_enc[q][kk*32 + kgroup*8 + j]  (zero for q >= 8)
#pragma unroll
    for (int s8 = 0; s8 < 8; ++s8) {
        const int s  = t * 8 + s8;
        const int kk = s >> 6;
        const int l  = s & 63;
        const int q  = l & 15;
        const int kg = l >> 4;
        bf16x8 bv;
        if (q < QDIM) {
            const float* wp = W_enc + q * EDIM + kk * 32 + kg * 8;
            v4f w0 = *(const v4f*)wp;
            v4f w1 = *(const v4f*)(wp + 4);
            bv[0] = f2bf(w0.x); bv[1] = f2bf(w0.y);
            bv[2] = f2bf(w0.z); bv[3] = f2bf(w0.w);
            bv[4] = f2bf(w1.x); bv[5] = f2bf(w1.y);
            bv[6] = f2bf(w1.z); bv[7] = f2bf(w1.w);
        } else {
            bv = (bf16x8){0, 0, 0, 0, 0, 0, 0, 0};
        }
        *(bf16x8*)&Blds[s * 8] = bv;
    }
    __syncthreads();

    // ---- encode: each wave MFMAs its own 16-token tile over K=1024 ----
    const int wtok0 = tok0 + wave * 16;
    const int arow  = lane & 15;          // token within tile (A row)
    const int kg    = lane >> 4;          // k-group (8 elems)

    v4f acc = (v4f){0.f, 0.f, 0.f, 0.f};
    const float* abase = x + (size_t)(wtok0 + arow) * EDIM + kg * 8;
#pragma unroll 8
    for (int kk = 0; kk < NKK; ++kk) {
        const float* ap = abase + kk * 32;
        v4f a0 = *(const v4f*)ap;
        v4f a1 = *(const v4f*)(ap + 4);
        bf16x8 av;
        av[0] = f2bf(a0.x); av[1] = f2bf(a0.y);
        av[2] = f2bf(a0.z); av[3] = f2bf(a0.w);
        av[4] = f2bf(a1.x); av[5] = f2bf(a1.y);
        av[6] = f2bf(a1.z); av[7] = f2bf(a1.w);
        bf16x8 bv = *(const bf16x8*)&Blds[(kk * 64 + lane) * 8];
        acc = __builtin_amdgcn_mfma_f32_16x16x32_bf16(av, bv, acc, 0, 0, 0);
    }

    // ---- epilogue: C[row=(lane>>4)*4+reg][col=lane&15=q] = angle ----
    // cos + cumprod across q = DPP scan across lanes 0..7 of each 16-row
    const int q = lane & 15;
#pragma unroll
    for (int r = 0; r < 4; ++r) {
        const int ltok = wave * 16 + kg * 4 + r;   // token within block
        float c = __cosf(acc[r]);

        float p = c;                       // q -> c0*...*cq
        p = scan_mul_step<1>(p, q);
        p = scan_mul_step<2>(p, q);
        p = scan_mul_step<4>(p, q);

        float b = (q == 0) ? 1.0f : c;     // lane 7 -> c1*...*c7
        b = scan_mul_step<1>(b, q);
        b = scan_mul_step<2>(b, q);
        b = scan_mul_step<4>(b, q);

        if (q >= 1 && q < QDIM) qv_s[ltok][q] = p;
        if (q == 7)             qv_s[ltok][0] = b;
    }
    __syncthreads();

    // ---- decode: thread owns e0 = t*4 for all 64 tokens (streaming) ----
    const int e0 = t * 4;
    v4f wdlo[4], wdhi[4];
#pragma unroll
    for (int j = 0; j < 4; ++j) {
        wdlo[j] = *(const v4f*)(W_dec + (e0 + j) * QDIM);
        wdhi[j] = *(const v4f*)(W_dec + (e0 + j) * QDIM + 4);
    }

#pragma unroll 4
    for (int i = 0; i < TOKPB; ++i) {
        v4f qlo = *(const v4f*)&qv_s[i][0];     // broadcast reads
        v4f qhi = *(const v4f*)&qv_s[i][4];
        v4f xv  = *(const v4f*)(x + (size_t)(tok0 + i) * EDIM + e0);  // L2-hot
        float od[4];
#pragma unroll
        for (int j = 0; j < 4; ++j) {
            v2f a = __builtin_elementwise_fma(
                        (v2f){qlo.x, qlo.y}, (v2f){wdlo[j].x, wdlo[j].y},
                        (v2f){xv[j], 0.f});
            a = __builtin_elementwise_fma((v2f){qlo.z, qlo.w},
                                          (v2f){wdlo[j].z, wdlo[j].w}, a);
            a = __builtin_elementwise_fma((v2f){qhi.x, qhi.y},
                                          (v2f){wdhi[j].x, wdhi[j].y}, a);
            a = __builtin_elementwise_fma((v2f){qhi.z, qhi.w},
                                          (v2f){wdhi[j].z, wdhi[j].w}, a);
            od[j] = a.x + a.y;
        }
        v4f o = (v4f){od[0], od[1], od[2], od[3]};
        __builtin_nontemporal_store(o, (v4f*)(out + (size_t)(tok0 + i) * EDIM + e0));
    }
}

extern "C" void kernel_launch(void* const* d_in, const int* in_sizes, int n_in,
                              void* d_out, int out_size, void* d_ws, size_t ws_size,
                              hipStream_t stream) {
    const float* x     = (const float*)d_in[0];
    const float* W_enc = (const float*)d_in[1];
    const float* W_dec = (const float*)d_in[2];
    float* out         = (float*)d_out;
    (void)d_ws; (void)ws_size;

    hipLaunchKernelGGL(qattn_kernel, dim3(GRID), dim3(BLOCK), 0, stream,
                       x, W_enc, W_dec, out);
}